// Round 12
// baseline (259.593 us; speedup 1.0000x reference)
//
#include <hip/hip_runtime.h>
#include <hip/hip_bf16.h>

// MultiHeadAttention: B=4, T=2048, D=512, H=8, K=64.
// Inputs fp32, output fp32, intermediates bf16.
// [0] cvt {x, w_qkv} -> bf16
// [1] gemm_bb: qkv = x @ w_qkv^T (q-part pre-scaled by 0.125*log2e)
// [2] attn_v5: causal flash attn, Q-tile 128, wave owns 32 q-rows (2 strips)
// [3] gemm_b64: out = attn @ w_proj^T + b_proj
//
// R12: attn was nearing an LDS-BW floor (each K/V frag read fed 1 MFMA).
// v5 doubles q-rows/wave -> halves K/V LDS reads + barriers per element.

typedef unsigned short u16;
typedef __attribute__((ext_vector_type(8))) __bf16 bf16x8;
typedef __attribute__((ext_vector_type(8))) unsigned short u16x8;
typedef __attribute__((ext_vector_type(4))) float f32x4;
typedef __attribute__((ext_vector_type(4))) unsigned u32x4;

#define DEV static __device__ __forceinline__

DEV void async16(const u16* g, u16* l) {  // global->LDS DMA, 16B/lane
  __builtin_amdgcn_global_load_lds(
      (const __attribute__((address_space(1))) unsigned int*)g,
      (__attribute__((address_space(3))) unsigned int*)l, 16, 0, 0);
}
DEV u16x8 gld8(const u16* p) { return *(const u16x8*)p; }
DEV void lst8(u16* p, u16x8 v) { *(u16x8*)p = v; }
DEV bf16x8 ldsld8(const u16* p) {
  return __builtin_bit_cast(bf16x8, *(const u16x8*)p);
}
DEV f32x4 mfma16(bf16x8 a, bf16x8 b, f32x4 c) {
  return __builtin_amdgcn_mfma_f32_16x16x32_bf16(a, b, c, 0, 0, 0);
}
DEV u16 f2b(float f) {  // fp32 -> bf16 RNE
  unsigned u = __builtin_bit_cast(unsigned, f);
  u += 0x7FFFu + ((u >> 16) & 1u);
  return (u16)(u >> 16);
}
DEV unsigned pk2(float x, float y) {  // v_cvt_pk_bf16_f32
  __hip_bfloat162 t = __float22bfloat162_rn(float2{x, y});
  unsigned r;
  __builtin_memcpy(&r, &t, 4);
  return r;
}
DEV u16x8 pack8(f32x4 a, f32x4 b) {
  u32x4 t;
  t[0] = pk2(a[0], a[1]);
  t[1] = pk2(a[2], a[3]);
  t[2] = pk2(b[0], b[1]);
  t[3] = pk2(b[2], b[3]);
  return __builtin_bit_cast(u16x8, t);
}

// ---------------------------------------------------------------------------
// fp32 -> bf16: x (8192x512) -> xb, w_qkv (1536x512) -> wqb (parked in d_out)
__global__ void cvt_all(const float* __restrict__ x, const float* __restrict__ wq,
                        u16* __restrict__ xb, u16* __restrict__ wqb) {
  constexpr long NX = 8192L * 512 / 8;
  constexpr long NQ = 1536L * 512 / 8;
  const long i = (long)blockIdx.x * 256 + threadIdx.x;
  if (i < NX) {
    const float* p = x + i * 8;
    *(u16x8*)(xb + i * 8) = pack8(*(const f32x4*)p, *(const f32x4*)(p + 4));
  } else if (i < NX + NQ) {
    const long j = i - NX;
    const float* p = wq + j * 8;
    *(u16x8*)(wqb + j * 8) = pack8(*(const f32x4*)p, *(const f32x4*)(p + 4));
  }
}

// ---------------------------------------------------------------------------
// gemm1: C[M,1536](bf16) = A[M,512](bf16) @ Bt[1536,512](bf16)^T.
// BM=BN=128, BK=64 (two 32-halves), both operands via async16 (R8-proven).
// Epilogue: cols < 512 (the q heads) scaled by 0.125*log2(e) so attn's
// softmax can use exp2 with no per-element multiply.
// ---------------------------------------------------------------------------
__global__ void gemm_bb(const u16* __restrict__ A, const u16* __restrict__ Bt,
                        u16* __restrict__ C, int N, int K) {
  __shared__ __align__(16) u16 As[2][128 * 32];
  __shared__ __align__(16) u16 Bs[2][128 * 32];

  const int t = threadIdx.x, lane = t & 63, w = t >> 6;
  const int lane15 = lane & 15, quad = lane >> 4;
  const int wr = w >> 1, wc = w & 1;
  const long row0 = (long)blockIdx.y * 128;
  const int col0 = blockIdx.x * 128;

  const int srow = w * 16 + (lane >> 2);
  const int scol = (lane & 3) * 8;
  const u16* Ag = A + (row0 + srow) * (long)K + scol;
  const u16* Bg = Bt + ((long)col0 + srow) * (long)K + scol;

  f32x4 acc[4][4];
#pragma unroll
  for (int i = 0; i < 4; i++)
#pragma unroll
    for (int j = 0; j < 4; j++) acc[i][j] = (f32x4)(0.0f);

  for (int k0 = 0; k0 < K; k0 += 64) {
    __syncthreads();
#pragma unroll
    for (int r = 0; r < 2; r++)
#pragma unroll
      for (int hf = 0; hf < 2; hf++) {
        async16(Ag + (long)r * 64 * K + k0 + hf * 32,
                &As[hf][(r * 64 + w * 16) * 32]);
        async16(Bg + (long)r * 64 * K + k0 + hf * 32,
                &Bs[hf][(r * 64 + w * 16) * 32]);
      }
    __syncthreads();

#pragma unroll
    for (int hf = 0; hf < 2; hf++) {
      bf16x8 a[4], b[4];
#pragma unroll
      for (int i = 0; i < 4; i++)
        a[i] = ldsld8(&As[hf][(wr * 64 + i * 16 + lane15) * 32 + quad * 8]);
#pragma unroll
      for (int j = 0; j < 4; j++)
        b[j] = ldsld8(&Bs[hf][(wc * 64 + j * 16 + lane15) * 32 + quad * 8]);
#pragma unroll
      for (int i = 0; i < 4; i++)
#pragma unroll
        for (int j = 0; j < 4; j++) acc[i][j] = mfma16(a[i], b[j], acc[i][j]);
    }
  }

#pragma unroll
  for (int i = 0; i < 4; i++)
#pragma unroll
    for (int j = 0; j < 4; j++) {
      const int col = col0 + wc * 64 + j * 16 + lane15;
      const float sc = (col < 512) ? 0.18033688f : 1.0f;  // q pre-scale
#pragma unroll
      for (int r = 0; r < 4; r++) {
        const long row = row0 + wr * 64 + i * 16 + quad * 4 + r;
        C[row * (long)N + col] = f2b(acc[i][j][r] * sc);
      }
    }
}

// ---------------------------------------------------------------------------
// gemm3: C[M,512](fp32) = A[M,512](bf16) @ Bt[512,512](fp32)^T + bias.
// BM=128, BN=64, BK=64. A via async16; B reg-prefetch + cvt. (R8-proven)
// ---------------------------------------------------------------------------
__global__ void gemm_b64(const u16* __restrict__ A, const float* __restrict__ Bt,
                         const float* __restrict__ bias, float* __restrict__ C,
                         int N, int K) {
  __shared__ __align__(16) u16 As[2][128 * 32];
  __shared__ __align__(16) u16 Bs[2][64 * 32];

  const int t = threadIdx.x, lane = t & 63, w = t >> 6;
  const int lane15 = lane & 15, quad = lane >> 4;
  const int wr = w >> 1, wc = w & 1;
  const long row0 = (long)blockIdx.y * 128;
  const int col0 = blockIdx.x * 64;

  const int srow = w * 16 + (lane >> 2);
  const int scol = (lane & 3) * 8;
  const u16* Ag = A + (row0 + srow) * (long)K + scol;

  const int brow = t >> 2, bc = (t & 3) * 16;
  const float* Bg = Bt + (long)(col0 + brow) * K + bc;
  u16* BsD = &Bs[bc >> 5][brow * 32 + (bc & 31)];

  f32x4 acc[4][2];
#pragma unroll
  for (int i = 0; i < 4; i++)
#pragma unroll
    for (int j = 0; j < 2; j++) acc[i][j] = (f32x4)(0.0f);

  f32x4 q0 = *(const f32x4*)Bg, q1 = *(const f32x4*)(Bg + 4);
  f32x4 q2 = *(const f32x4*)(Bg + 8), q3 = *(const f32x4*)(Bg + 12);

  for (int k0 = 0; k0 < K; k0 += 64) {
    __syncthreads();
#pragma unroll
    for (int r = 0; r < 2; r++)
#pragma unroll
      for (int hf = 0; hf < 2; hf++)
        async16(Ag + (long)r * 64 * K + k0 + hf * 32,
                &As[hf][(r * 64 + w * 16) * 32]);
    lst8(BsD, pack8(q0, q1));
    lst8(BsD + 8, pack8(q2, q3));
    __syncthreads();

    {
      const int kp = (k0 + 64 < K) ? k0 + 64 : k0;
      q0 = *(const f32x4*)(Bg + kp);     q1 = *(const f32x4*)(Bg + kp + 4);
      q2 = *(const f32x4*)(Bg + kp + 8); q3 = *(const f32x4*)(Bg + kp + 12);
    }

#pragma unroll
    for (int hf = 0; hf < 2; hf++) {
      bf16x8 a[4], b[2];
#pragma unroll
      for (int i = 0; i < 4; i++)
        a[i] = ldsld8(&As[hf][(wr * 64 + i * 16 + lane15) * 32 + quad * 8]);
#pragma unroll
      for (int j = 0; j < 2; j++)
        b[j] = ldsld8(&Bs[hf][(wc * 32 + j * 16 + lane15) * 32 + quad * 8]);
#pragma unroll
      for (int i = 0; i < 4; i++)
#pragma unroll
        for (int j = 0; j < 2; j++) acc[i][j] = mfma16(a[i], b[j], acc[i][j]);
    }
  }

#pragma unroll
  for (int i = 0; i < 4; i++)
#pragma unroll
    for (int j = 0; j < 2; j++) {
      const int col = col0 + wc * 32 + j * 16 + lane15;
      const float bv = bias[col];
#pragma unroll
      for (int r = 0; r < 4; r++) {
        const long row = row0 + wr * 64 + i * 16 + quad * 4 + r;
        C[row * (long)N + col] = acc[i][j][r] + bv;
      }
    }
}

// ---------------------------------------------------------------------------
// attn_v5: Q-tile 128, 256 threads / 4 waves; wave w owns TWO 16-row q-strips
// (rows qt*128 + sp*64 + w*16, sp=0,1) -> each K/V LDS frag read feeds 2
// MFMAs, barriers & staging per element halve. q pre-scaled -> exp2 direct.
// 512 blocks, longest-first (qt descending) for makespan.
// ---------------------------------------------------------------------------
__global__ void attn_v5(const u16* __restrict__ qkv, u16* __restrict__ out) {
  constexpr int T = 2048, LD = 1536;
  __shared__ __align__(16) u16 Ks[64 * 72];
  __shared__ __align__(16) u16 Vt[64 * 72];
  __shared__ __align__(16) u16 Ps[4][2][16 * 72];

  const int t = threadIdx.x, lane = t & 63, w = t >> 6;
  const int lane15 = lane & 15, quad = lane >> 4;

  const int bx = blockIdx.x;          // 0..511
  const int qt = 15 - (bx >> 5);      // longest blocks dispatch first
  const int h = bx & 7, b = (bx >> 3) & 3;
  const long base = (long)b * T * LD;

  // Q A-frags for both strips, straight from global
  bf16x8 qa[2][2];
#pragma unroll
  for (int sp = 0; sp < 2; sp++) {
    const u16* gq = qkv + base +
                    (long)(qt * 128 + sp * 64 + w * 16 + lane15) * LD +
                    h * 64 + quad * 8;
    qa[sp][0] = __builtin_bit_cast(bf16x8, *(const u16x8*)gq);
    qa[sp][1] = __builtin_bit_cast(bf16x8, *(const u16x8*)(gq + 32));
  }

  const int srow = t >> 3, sc8 = (t & 7) * 8;  // K staging rows {srow, srow+32}
  const int vs = t >> 2, vd0 = (t & 3) * 16;   // V staging

  const int nsb = 2 * qt + 2;

  u16x8 kr0, kr1, vr0, vr1;  // prefetch s-tile 0
  {
    const u16* gk = qkv + base + (long)srow * LD + 512 + h * 64 + sc8;
    const u16* gv = qkv + base + (long)vs * LD + 1024 + h * 64 + vd0;
    kr0 = gld8(gk); kr1 = gld8(gk + (long)32 * LD);
    vr0 = gld8(gv); vr1 = gld8(gv + 8);
  }

  float lp[2][4] = {{0, 0, 0, 0}, {0, 0, 0, 0}};
  f32x4 o[2][4];
#pragma unroll
  for (int sp = 0; sp < 2; sp++)
#pragma unroll
    for (int j = 0; j < 4; j++) o[sp][j] = (f32x4)(0.0f);

  for (int sb = 0; sb < nsb; ++sb) {
    __syncthreads();  // previous iteration's LDS reads complete
    lst8(&Ks[srow * 72 + sc8], kr0);
    lst8(&Ks[(srow + 32) * 72 + sc8], kr1);
#pragma unroll
    for (int ii = 0; ii < 8; ii++) {
      const int d = vd0 + ii;
      Vt[d * 72 + (vs ^ (((d >> 3) & 7) << 3))] = vr0[ii];
    }
#pragma unroll
    for (int ii = 0; ii < 8; ii++) {
      const int d = vd0 + 8 + ii;
      Vt[d * 72 + (vs ^ (((d >> 3) & 7) << 3))] = vr1[ii];
    }
    __syncthreads();  // tiles visible

    {  // prefetch next s-tile under compute (clamped)
      const int nx = (sb + 1 < nsb) ? sb + 1 : sb;
      const u16* gk = qkv + base + (long)(nx * 64 + srow) * LD + 512 + h * 64 + sc8;
      const u16* gv = qkv + base + (long)(nx * 64 + vs) * LD + 1024 + h * 64 + vd0;
      kr0 = gld8(gk); kr1 = gld8(gk + (long)32 * LD);
      vr0 = gld8(gv); vr1 = gld8(gv + 8);
    }

#pragma unroll
    for (int sp = 0; sp < 2; sp++) {
      if (sb > 2 * qt + sp) continue;  // strip fully masked (uniform branch)

      // S strip (16 q x 64 s)
      f32x4 sf[4];
#pragma unroll
      for (int j = 0; j < 4; j++) {
        f32x4 z = (f32x4)(0.0f);
        z = mfma16(qa[sp][0], ldsld8(&Ks[(j * 16 + lane15) * 72 + quad * 8]), z);
        sf[j] = mfma16(qa[sp][1],
                       ldsld8(&Ks[(j * 16 + lane15) * 72 + quad * 8 + 32]), z);
      }

      // p = exp2(s) (q pre-scaled by 0.125*log2e); mask only on diag tile
      if (sb == 2 * qt + sp) {
        const int qrow_base = qt * 128 + sp * 64 + w * 16 + quad * 4;
        const int scol_base = sb * 64 + lane15;
#pragma unroll
        for (int j = 0; j < 4; j++)
#pragma unroll
          for (int r = 0; r < 4; r++) {
            float p = exp2f(sf[j][r]);
            if (scol_base + j * 16 > qrow_base + r) p = 0.0f;
            sf[j][r] = p;
            lp[sp][r] += p;
          }
      } else {
#pragma unroll
        for (int j = 0; j < 4; j++)
#pragma unroll
          for (int r = 0; r < 4; r++) {
            const float p = exp2f(sf[j][r]);
            sf[j][r] = p;
            lp[sp][r] += p;
          }
      }

      // P: C-layout -> per-wave-per-strip LDS chunk -> A-layout (same-wave
      // DS in-order; fences stop compiler reordering)
      u16* myP = Ps[w][sp];
#pragma unroll
      for (int j = 0; j < 4; j++)
#pragma unroll
        for (int r = 0; r < 4; r++)
          myP[(quad * 4 + r) * 72 + j * 16 + lane15] = f2b(sf[j][r]);
      __asm__ __volatile__("" ::: "memory");
      const bf16x8 pa0 = ldsld8(&myP[lane15 * 72 + quad * 8]);
      const bf16x8 pa1 = ldsld8(&myP[lane15 * 72 + quad * 8 + 32]);
      __asm__ __volatile__("" ::: "memory");

      // O += P @ V from swizzled Vt
#pragma unroll
      for (int j = 0; j < 4; j++) {
        const int d0 = j * 16 + lane15;
        const int swz = ((d0 >> 3) & 7) << 3;
        o[sp][j] = mfma16(pa0, ldsld8(&Vt[d0 * 72 + ((quad * 8) ^ swz)]), o[sp][j]);
        o[sp][j] =
            mfma16(pa1, ldsld8(&Vt[d0 * 72 + ((quad * 8 + 32) ^ swz)]), o[sp][j]);
      }
    }
  }

  // cross-lane row-sum reductions, then store both strips
#pragma unroll
  for (int off = 1; off < 16; off <<= 1)
#pragma unroll
    for (int sp = 0; sp < 2; sp++)
#pragma unroll
      for (int r = 0; r < 4; r++) lp[sp][r] += __shfl_xor(lp[sp][r], off);

#pragma unroll
  for (int sp = 0; sp < 2; sp++) {
    const long orow0 = (long)b * T + qt * 128 + sp * 64 + w * 16;
    float inv[4];
#pragma unroll
    for (int r = 0; r < 4; r++) inv[r] = 1.0f / lp[sp][r];
#pragma unroll
    for (int j = 0; j < 4; j++)
#pragma unroll
      for (int r = 0; r < 4; r++)
        out[(orow0 + quad * 4 + r) * 512 + h * 64 + j * 16 + lane15] =
            f2b(o[sp][j][r] * inv[r]);
  }
}

// ---------------------------------------------------------------------------
extern "C" void kernel_launch(void* const* d_in, const int* in_sizes, int n_in,
                              void* d_out, int out_size, void* d_ws, size_t ws_size,
                              hipStream_t stream) {
  const float* x      = (const float*)d_in[0];  // [4,2048,512] fp32
  const float* w_qkv  = (const float*)d_in[1];  // [1536,512]  fp32
  const float* w_proj = (const float*)d_in[2];  // [512,512]   fp32
  const float* b_proj = (const float*)d_in[3];  // [512]       fp32
  float* out = (float*)d_out;                   // [4,2048,512] fp32

  u16* qkv = (u16*)d_ws;                  // [8192 x 1536] bf16 = 24 MiB
  u16* xb  = qkv + (size_t)8192 * 1536;   // [8192 x 512]  bf16 =  8 MiB
                                          // (x_bf16, then attn output)
  u16* wqb = (u16*)d_out;                 // w_qkv bf16 parked in d_out
                                          // (dead until gemm3 writes)

  // [0] convert x and w_qkv to bf16
  cvt_all<<<2432, 256, 0, stream>>>(x, w_qkv, xb, wqb);
  // [1] qkv projection (all-bf16, q pre-scaled in epilogue)
  gemm_bb<<<dim3(12, 64), 256, 0, stream>>>(xb, wqb, qkv, 1536, 512);
  // [2] causal flash attention (overwrites xb)
  attn_v5<<<512, 256, 0, stream>>>(qkv, xb);
  // [3] output projection + bias -> fp32 d_out
  gemm_b64<<<dim3(8, 64), 256, 0, stream>>>(xb, w_proj, b_proj, out, 512, 512);
}

// Round 13
// 160.945 us; speedup vs baseline: 1.6129x; 1.6129x over previous
//
#include <hip/hip_runtime.h>
#include <hip/hip_bf16.h>

// MultiHeadAttention: B=4, T=2048, D=512, H=8, K=64.
// Inputs fp32, output fp32, intermediates bf16.
// [0] cvt {x, w_qkv} -> bf16
// [1] gemm_bb: qkv = x @ w_qkv^T (XCD-swizzled grid; q pre-scaled)
// [2] attn_v3 (R7/R8-proven, exp2 direct)
// [3] gemm_b64: out = attn @ w_proj^T + b_proj (XCD-swizzled grid)
//
// R13: v5 reverted (register spill -> 95 MB scratch writes, 155 µs).
// GEMMs get XCD-aware swizzle: all col-tiles of a row-tile share i%8 ->
// same XCD L2 -> A fetched ~once per row-tile instead of 12x/8x.

typedef unsigned short u16;
typedef __attribute__((ext_vector_type(8))) __bf16 bf16x8;
typedef __attribute__((ext_vector_type(8))) unsigned short u16x8;
typedef __attribute__((ext_vector_type(4))) float f32x4;
typedef __attribute__((ext_vector_type(4))) unsigned u32x4;

#define DEV static __device__ __forceinline__

DEV void async16(const u16* g, u16* l) {  // global->LDS DMA, 16B/lane
  __builtin_amdgcn_global_load_lds(
      (const __attribute__((address_space(1))) unsigned int*)g,
      (__attribute__((address_space(3))) unsigned int*)l, 16, 0, 0);
}
DEV u16x8 gld8(const u16* p) { return *(const u16x8*)p; }
DEV void lst8(u16* p, u16x8 v) { *(u16x8*)p = v; }
DEV bf16x8 ldsld8(const u16* p) {
  return __builtin_bit_cast(bf16x8, *(const u16x8*)p);
}
DEV f32x4 mfma16(bf16x8 a, bf16x8 b, f32x4 c) {
  return __builtin_amdgcn_mfma_f32_16x16x32_bf16(a, b, c, 0, 0, 0);
}
DEV u16 f2b(float f) {  // fp32 -> bf16 RNE
  unsigned u = __builtin_bit_cast(unsigned, f);
  u += 0x7FFFu + ((u >> 16) & 1u);
  return (u16)(u >> 16);
}
DEV unsigned pk2(float x, float y) {  // v_cvt_pk_bf16_f32
  __hip_bfloat162 t = __float22bfloat162_rn(float2{x, y});
  unsigned r;
  __builtin_memcpy(&r, &t, 4);
  return r;
}
DEV u16x8 pack8(f32x4 a, f32x4 b) {
  u32x4 t;
  t[0] = pk2(a[0], a[1]);
  t[1] = pk2(a[2], a[3]);
  t[2] = pk2(b[0], b[1]);
  t[3] = pk2(b[2], b[3]);
  return __builtin_bit_cast(u16x8, t);
}

// ---------------------------------------------------------------------------
// fp32 -> bf16: x (8192x512) -> xb, w_qkv (1536x512) -> wqb (parked in d_out)
__global__ void cvt_all(const float* __restrict__ x, const float* __restrict__ wq,
                        u16* __restrict__ xb, u16* __restrict__ wqb) {
  constexpr long NX = 8192L * 512 / 8;
  constexpr long NQ = 1536L * 512 / 8;
  const long i = (long)blockIdx.x * 256 + threadIdx.x;
  if (i < NX) {
    const float* p = x + i * 8;
    *(u16x8*)(xb + i * 8) = pack8(*(const f32x4*)p, *(const f32x4*)(p + 4));
  } else if (i < NX + NQ) {
    const long j = i - NX;
    const float* p = wq + j * 8;
    *(u16x8*)(wqb + j * 8) = pack8(*(const f32x4*)p, *(const f32x4*)(p + 4));
  }
}

// ---------------------------------------------------------------------------
// gemm1: C[M,1536](bf16) = A[M,512](bf16) @ Bt[1536,512](bf16)^T.
// BM=BN=128, BK=64 (two 32-halves), both operands via async16 (R8-proven).
// Grid: 768 linear blocks, XCD-swizzled: rt = (i&7)|(((i>>3)&7)<<3), ct=i>>6
// -> all 12 col-tiles of one row-tile share i%8 (same XCD L2).
// Epilogue: q cols (<512) pre-scaled by 0.125*log2(e) for attn's exp2.
// ---------------------------------------------------------------------------
__global__ void gemm_bb(const u16* __restrict__ A, const u16* __restrict__ Bt,
                        u16* __restrict__ C, int N, int K) {
  __shared__ __align__(16) u16 As[2][128 * 32];
  __shared__ __align__(16) u16 Bs[2][128 * 32];

  const int t = threadIdx.x, lane = t & 63, w = t >> 6;
  const int lane15 = lane & 15, quad = lane >> 4;
  const int wr = w >> 1, wc = w & 1;

  const int i = blockIdx.x;
  const int rt = (i & 7) | (((i >> 3) & 7) << 3);  // 0..63
  const int ct = i >> 6;                           // 0..11
  const long row0 = (long)rt * 128;
  const int col0 = ct * 128;

  const int srow = w * 16 + (lane >> 2);
  const int scol = (lane & 3) * 8;
  const u16* Ag = A + (row0 + srow) * (long)K + scol;
  const u16* Bg = Bt + ((long)col0 + srow) * (long)K + scol;

  f32x4 acc[4][4];
#pragma unroll
  for (int ii = 0; ii < 4; ii++)
#pragma unroll
    for (int j = 0; j < 4; j++) acc[ii][j] = (f32x4)(0.0f);

  for (int k0 = 0; k0 < K; k0 += 64) {
    __syncthreads();
#pragma unroll
    for (int r = 0; r < 2; r++)
#pragma unroll
      for (int hf = 0; hf < 2; hf++) {
        async16(Ag + (long)r * 64 * K + k0 + hf * 32,
                &As[hf][(r * 64 + w * 16) * 32]);
        async16(Bg + (long)r * 64 * K + k0 + hf * 32,
                &Bs[hf][(r * 64 + w * 16) * 32]);
      }
    __syncthreads();

#pragma unroll
    for (int hf = 0; hf < 2; hf++) {
      bf16x8 a[4], b[4];
#pragma unroll
      for (int ii = 0; ii < 4; ii++)
        a[ii] = ldsld8(&As[hf][(wr * 64 + ii * 16 + lane15) * 32 + quad * 8]);
#pragma unroll
      for (int j = 0; j < 4; j++)
        b[j] = ldsld8(&Bs[hf][(wc * 64 + j * 16 + lane15) * 32 + quad * 8]);
#pragma unroll
      for (int ii = 0; ii < 4; ii++)
#pragma unroll
        for (int j = 0; j < 4; j++) acc[ii][j] = mfma16(a[ii], b[j], acc[ii][j]);
    }
  }

#pragma unroll
  for (int ii = 0; ii < 4; ii++)
#pragma unroll
    for (int j = 0; j < 4; j++) {
      const int col = col0 + wc * 64 + j * 16 + lane15;
      const float sc = (col < 512) ? 0.18033688f : 1.0f;  // q pre-scale
#pragma unroll
      for (int r = 0; r < 4; r++) {
        const long row = row0 + wr * 64 + ii * 16 + quad * 4 + r;
        C[row * (long)N + col] = f2b(acc[ii][j][r] * sc);
      }
    }
}

// ---------------------------------------------------------------------------
// gemm3: C[M,512](fp32) = A[M,512](bf16) @ Bt[512,512](fp32)^T + bias.
// BM=128, BN=64, BK=64. A via async16; B reg-prefetch + cvt. (R8-proven)
// Grid: 512 linear blocks, XCD-swizzled like gemm1 (ct = i>>6 in [0,8)).
// ---------------------------------------------------------------------------
__global__ void gemm_b64(const u16* __restrict__ A, const float* __restrict__ Bt,
                         const float* __restrict__ bias, float* __restrict__ C,
                         int N, int K) {
  __shared__ __align__(16) u16 As[2][128 * 32];
  __shared__ __align__(16) u16 Bs[2][64 * 32];

  const int t = threadIdx.x, lane = t & 63, w = t >> 6;
  const int lane15 = lane & 15, quad = lane >> 4;
  const int wr = w >> 1, wc = w & 1;

  const int i = blockIdx.x;
  const int rt = (i & 7) | (((i >> 3) & 7) << 3);  // 0..63
  const int ct = i >> 6;                           // 0..7
  const long row0 = (long)rt * 128;
  const int col0 = ct * 64;

  const int srow = w * 16 + (lane >> 2);
  const int scol = (lane & 3) * 8;
  const u16* Ag = A + (row0 + srow) * (long)K + scol;

  const int brow = t >> 2, bc = (t & 3) * 16;
  const float* Bg = Bt + (long)(col0 + brow) * K + bc;
  u16* BsD = &Bs[bc >> 5][brow * 32 + (bc & 31)];

  f32x4 acc[4][2];
#pragma unroll
  for (int ii = 0; ii < 4; ii++)
#pragma unroll
    for (int j = 0; j < 2; j++) acc[ii][j] = (f32x4)(0.0f);

  f32x4 q0 = *(const f32x4*)Bg, q1 = *(const f32x4*)(Bg + 4);
  f32x4 q2 = *(const f32x4*)(Bg + 8), q3 = *(const f32x4*)(Bg + 12);

  for (int k0 = 0; k0 < K; k0 += 64) {
    __syncthreads();
#pragma unroll
    for (int r = 0; r < 2; r++)
#pragma unroll
      for (int hf = 0; hf < 2; hf++)
        async16(Ag + (long)r * 64 * K + k0 + hf * 32,
                &As[hf][(r * 64 + w * 16) * 32]);
    lst8(BsD, pack8(q0, q1));
    lst8(BsD + 8, pack8(q2, q3));
    __syncthreads();

    {
      const int kp = (k0 + 64 < K) ? k0 + 64 : k0;
      q0 = *(const f32x4*)(Bg + kp);     q1 = *(const f32x4*)(Bg + kp + 4);
      q2 = *(const f32x4*)(Bg + kp + 8); q3 = *(const f32x4*)(Bg + kp + 12);
    }

#pragma unroll
    for (int hf = 0; hf < 2; hf++) {
      bf16x8 a[4], b[2];
#pragma unroll
      for (int ii = 0; ii < 4; ii++)
        a[ii] = ldsld8(&As[hf][(wr * 64 + ii * 16 + lane15) * 32 + quad * 8]);
#pragma unroll
      for (int j = 0; j < 2; j++)
        b[j] = ldsld8(&Bs[hf][(wc * 32 + j * 16 + lane15) * 32 + quad * 8]);
#pragma unroll
      for (int ii = 0; ii < 4; ii++)
#pragma unroll
        for (int j = 0; j < 2; j++) acc[ii][j] = mfma16(a[ii], b[j], acc[ii][j]);
    }
  }

#pragma unroll
  for (int ii = 0; ii < 4; ii++)
#pragma unroll
    for (int j = 0; j < 2; j++) {
      const int col = col0 + wc * 32 + j * 16 + lane15;
      const float bv = bias[col];
#pragma unroll
      for (int r = 0; r < 4; r++) {
        const long row = row0 + wr * 64 + ii * 16 + quad * 4 + r;
        C[row * (long)N + col] = acc[ii][j][r] + bv;
      }
    }
}

// ---------------------------------------------------------------------------
// Causal flash attention v3 (R7/R8-proven ~58 µs). q pre-scaled -> exp2 direct.
// ---------------------------------------------------------------------------
__global__ void attn_v3(const u16* __restrict__ qkv, u16* __restrict__ out) {
  constexpr int T = 2048, LD = 1536;
  __shared__ __align__(16) u16 Ks[64 * 72];
  __shared__ __align__(16) u16 Vt[64 * 72];
  __shared__ __align__(16) u16 Ps[4][16 * 72];

  const int t = threadIdx.x, lane = t & 63, w = t >> 6;
  const int lane15 = lane & 15, quad = lane >> 4;

  const int i = blockIdx.x;
  int qb = i & 31;
  if (i >= 512) qb = 31 - qb;  // load-balance
  const int h = (i >> 5) & 7;
  const int b = (i >> 8) & 3;
  const long base = (long)b * T * LD;

  const u16* gq =
      qkv + base + (long)(qb * 64 + w * 16 + lane15) * LD + h * 64 + quad * 8;
  const bf16x8 qa0 = __builtin_bit_cast(bf16x8, *(const u16x8*)gq);
  const bf16x8 qa1 = __builtin_bit_cast(bf16x8, *(const u16x8*)(gq + 32));

  const int srow = t >> 3, sc8 = (t & 7) * 8;
  const int vs = t >> 2, vd0 = (t & 3) * 16;

  const int nsb = qb + 1;

  u16x8 kr0, kr1, vr0, vr1;
  {
    const u16* gk = qkv + base + (long)srow * LD + 512 + h * 64 + sc8;
    const u16* gv = qkv + base + (long)vs * LD + 1024 + h * 64 + vd0;
    kr0 = gld8(gk); kr1 = gld8(gk + (long)32 * LD);
    vr0 = gld8(gv); vr1 = gld8(gv + 8);
  }

  float lp[4] = {0.0f, 0.0f, 0.0f, 0.0f};
  f32x4 o[4];
#pragma unroll
  for (int j = 0; j < 4; j++) o[j] = (f32x4)(0.0f);

  const int qrow_base = qb * 64 + w * 16 + quad * 4;

  for (int sb = 0; sb < nsb; ++sb) {
    __syncthreads();
    lst8(&Ks[srow * 72 + sc8], kr0);
    lst8(&Ks[(srow + 32) * 72 + sc8], kr1);
#pragma unroll
    for (int ii = 0; ii < 8; ii++) {
      const int d = vd0 + ii;
      Vt[d * 72 + (vs ^ (((d >> 3) & 7) << 3))] = vr0[ii];
    }
#pragma unroll
    for (int ii = 0; ii < 8; ii++) {
      const int d = vd0 + 8 + ii;
      Vt[d * 72 + (vs ^ (((d >> 3) & 7) << 3))] = vr1[ii];
    }
    __syncthreads();

    {
      const int sp = (sb + 1 < nsb) ? sb + 1 : sb;
      const u16* gk = qkv + base + (long)(sp * 64 + srow) * LD + 512 + h * 64 + sc8;
      const u16* gv = qkv + base + (long)(sp * 64 + vs) * LD + 1024 + h * 64 + vd0;
      kr0 = gld8(gk); kr1 = gld8(gk + (long)32 * LD);
      vr0 = gld8(gv); vr1 = gld8(gv + 8);
    }

    f32x4 sf[4];
#pragma unroll
    for (int j = 0; j < 4; j++) {
      f32x4 z = (f32x4)(0.0f);
      z = mfma16(qa0, ldsld8(&Ks[(j * 16 + lane15) * 72 + quad * 8]), z);
      sf[j] = mfma16(qa1, ldsld8(&Ks[(j * 16 + lane15) * 72 + quad * 8 + 32]), z);
    }

    if (sb == qb) {
      const int scol_base = sb * 64 + lane15;
#pragma unroll
      for (int j = 0; j < 4; j++)
#pragma unroll
        for (int r = 0; r < 4; r++) {
          float p = exp2f(sf[j][r]);
          if (scol_base + j * 16 > qrow_base + r) p = 0.0f;
          sf[j][r] = p;
          lp[r] += p;
        }
    } else {
#pragma unroll
      for (int j = 0; j < 4; j++)
#pragma unroll
        for (int r = 0; r < 4; r++) {
          const float p = exp2f(sf[j][r]);
          sf[j][r] = p;
          lp[r] += p;
        }
    }

    u16* myP = Ps[w];
#pragma unroll
    for (int j = 0; j < 4; j++)
#pragma unroll
      for (int r = 0; r < 4; r++)
        myP[(quad * 4 + r) * 72 + j * 16 + lane15] = f2b(sf[j][r]);
    __asm__ __volatile__("" ::: "memory");
    const bf16x8 pa0 = ldsld8(&myP[lane15 * 72 + quad * 8]);
    const bf16x8 pa1 = ldsld8(&myP[lane15 * 72 + quad * 8 + 32]);
    __asm__ __volatile__("" ::: "memory");

#pragma unroll
    for (int j = 0; j < 4; j++) {
      const int d0 = j * 16 + lane15;
      const int swz = ((d0 >> 3) & 7) << 3;
      o[j] = mfma16(pa0, ldsld8(&Vt[d0 * 72 + ((quad * 8) ^ swz)]), o[j]);
      o[j] = mfma16(pa1, ldsld8(&Vt[d0 * 72 + ((quad * 8 + 32) ^ swz)]), o[j]);
    }
  }

#pragma unroll
  for (int off = 1; off < 16; off <<= 1)
#pragma unroll
    for (int r = 0; r < 4; r++) lp[r] += __shfl_xor(lp[r], off);

  const long orow0 = (long)b * T + qb * 64 + w * 16;
  float inv[4];
#pragma unroll
  for (int r = 0; r < 4; r++) inv[r] = 1.0f / lp[r];
#pragma unroll
  for (int j = 0; j < 4; j++)
#pragma unroll
    for (int r = 0; r < 4; r++)
      out[(orow0 + quad * 4 + r) * 512 + h * 64 + j * 16 + lane15] =
          f2b(o[j][r] * inv[r]);
}

// ---------------------------------------------------------------------------
extern "C" void kernel_launch(void* const* d_in, const int* in_sizes, int n_in,
                              void* d_out, int out_size, void* d_ws, size_t ws_size,
                              hipStream_t stream) {
  const float* x      = (const float*)d_in[0];  // [4,2048,512] fp32
  const float* w_qkv  = (const float*)d_in[1];  // [1536,512]  fp32
  const float* w_proj = (const float*)d_in[2];  // [512,512]   fp32
  const float* b_proj = (const float*)d_in[3];  // [512]       fp32
  float* out = (float*)d_out;                   // [4,2048,512] fp32

  u16* qkv = (u16*)d_ws;                  // [8192 x 1536] bf16 = 24 MiB
  u16* xb  = qkv + (size_t)8192 * 1536;   // [8192 x 512]  bf16 =  8 MiB
                                          // (x_bf16, then attn output)
  u16* wqb = (u16*)d_out;                 // w_qkv bf16 parked in d_out
                                          // (dead until gemm3 writes)

  // [0] convert x and w_qkv to bf16
  cvt_all<<<2432, 256, 0, stream>>>(x, w_qkv, xb, wqb);
  // [1] qkv projection (all-bf16, XCD-swizzled, q pre-scaled)
  gemm_bb<<<768, 256, 0, stream>>>(xb, wqb, qkv, 1536, 512);
  // [2] causal flash attention (overwrites xb)
  attn_v3<<<1024, 256, 0, stream>>>(qkv, xb);
  // [3] output projection + bias -> fp32 d_out (XCD-swizzled)
  gemm_b64<<<512, 256, 0, stream>>>(xb, w_proj, b_proj, out, 512, 512);
}

// Round 14
// 153.930 us; speedup vs baseline: 1.6864x; 1.0456x over previous
//
#include <hip/hip_runtime.h>
#include <hip/hip_bf16.h>

// MultiHeadAttention: B=4, T=2048, D=512, H=8, K=64.
// Inputs fp32, output fp32, intermediates bf16.
// [0] cvt {x, w_qkv} -> bf16
// [1] gemm_bb: qk = x@w_qkv^T (q pre-scaled); v written TRANSPOSED to vT
// [2] attn_v6: flash attn; K and V^T both b128-staged (no in-kernel transpose)
// [3] gemm_b64: out = attn @ w_proj^T + b_proj
//
// R14: attn VALU diet. v3's inner loop spent ~80 inst on manual f2b RNE and
// ~40 on V-transpose scalar stores; both eliminated (pk2 packing + gemm1-side
// V pre-transpose). ws: qk 16 MiB + vT 8 MiB + xb 8 MiB = 32 MiB.

typedef unsigned short u16;
typedef __attribute__((ext_vector_type(8))) __bf16 bf16x8;
typedef __attribute__((ext_vector_type(8))) unsigned short u16x8;
typedef __attribute__((ext_vector_type(4))) unsigned short u16x4;
typedef __attribute__((ext_vector_type(4))) float f32x4;
typedef __attribute__((ext_vector_type(4))) unsigned u32x4;
typedef __attribute__((ext_vector_type(2))) unsigned u32x2;

#define DEV static __device__ __forceinline__

DEV void async16(const u16* g, u16* l) {  // global->LDS DMA, 16B/lane
  __builtin_amdgcn_global_load_lds(
      (const __attribute__((address_space(1))) unsigned int*)g,
      (__attribute__((address_space(3))) unsigned int*)l, 16, 0, 0);
}
DEV u16x8 gld8(const u16* p) { return *(const u16x8*)p; }
DEV void lst8(u16* p, u16x8 v) { *(u16x8*)p = v; }
DEV bf16x8 ldsld8(const u16* p) {
  return __builtin_bit_cast(bf16x8, *(const u16x8*)p);
}
DEV f32x4 mfma16(bf16x8 a, bf16x8 b, f32x4 c) {
  return __builtin_amdgcn_mfma_f32_16x16x32_bf16(a, b, c, 0, 0, 0);
}
DEV u16 f2b(float f) {  // fp32 -> bf16 RNE (epilogue-only)
  unsigned u = __builtin_bit_cast(unsigned, f);
  u += 0x7FFFu + ((u >> 16) & 1u);
  return (u16)(u >> 16);
}
DEV unsigned pk2(float x, float y) {  // v_cvt_pk_bf16_f32: low=x, high=y
  __hip_bfloat162 t = __float22bfloat162_rn(float2{x, y});
  unsigned r;
  __builtin_memcpy(&r, &t, 4);
  return r;
}
DEV u16x8 pack8(f32x4 a, f32x4 b) {
  u32x4 t;
  t[0] = pk2(a[0], a[1]);
  t[1] = pk2(a[2], a[3]);
  t[2] = pk2(b[0], b[1]);
  t[3] = pk2(b[2], b[3]);
  return __builtin_bit_cast(u16x8, t);
}

// ---------------------------------------------------------------------------
// fp32 -> bf16: x (8192x512) -> xb, w_qkv (1536x512) -> wqb (parked in d_out)
__global__ void cvt_all(const float* __restrict__ x, const float* __restrict__ wq,
                        u16* __restrict__ xb, u16* __restrict__ wqb) {
  constexpr long NX = 8192L * 512 / 8;
  constexpr long NQ = 1536L * 512 / 8;
  const long i = (long)blockIdx.x * 256 + threadIdx.x;
  if (i < NX) {
    const float* p = x + i * 8;
    *(u16x8*)(xb + i * 8) = pack8(*(const f32x4*)p, *(const f32x4*)(p + 4));
  } else if (i < NX + NQ) {
    const long j = i - NX;
    const float* p = wq + j * 8;
    *(u16x8*)(wqb + j * 8) = pack8(*(const f32x4*)p, *(const f32x4*)(p + 4));
  }
}

// ---------------------------------------------------------------------------
// gemm1: qkv projection. A[M,512](bf16) @ Bt[1536,512](bf16)^T.
// BM=BN=128, BK=64; both operands async16; XCD-swizzled grid (rt shares i%8).
// Output routing (block-uniform on col0):
//   cols <1024  -> qk[row*1024 + col], q cols (<512) scaled by 0.125*log2e
//   cols >=1024 -> vT[b][col-1024][s] (V transposed; pk2-packed 8B stores)
// ---------------------------------------------------------------------------
__global__ void gemm_bb(const u16* __restrict__ A, const u16* __restrict__ Bt,
                        u16* __restrict__ qk, u16* __restrict__ vT, int K) {
  __shared__ __align__(16) u16 As[2][128 * 32];
  __shared__ __align__(16) u16 Bs[2][128 * 32];

  const int t = threadIdx.x, lane = t & 63, w = t >> 6;
  const int lane15 = lane & 15, quad = lane >> 4;
  const int wr = w >> 1, wc = w & 1;

  const int i = blockIdx.x;
  const int rt = (i & 7) | (((i >> 3) & 7) << 3);  // 0..63
  const int ct = i >> 6;                           // 0..11
  const long row0 = (long)rt * 128;
  const int col0 = ct * 128;

  const int srow = w * 16 + (lane >> 2);
  const int scol = (lane & 3) * 8;
  const u16* Ag = A + (row0 + srow) * (long)K + scol;
  const u16* Bg = Bt + ((long)col0 + srow) * (long)K + scol;

  f32x4 acc[4][4];
#pragma unroll
  for (int ii = 0; ii < 4; ii++)
#pragma unroll
    for (int j = 0; j < 4; j++) acc[ii][j] = (f32x4)(0.0f);

  for (int k0 = 0; k0 < K; k0 += 64) {
    __syncthreads();
#pragma unroll
    for (int r = 0; r < 2; r++)
#pragma unroll
      for (int hf = 0; hf < 2; hf++) {
        async16(Ag + (long)r * 64 * K + k0 + hf * 32,
                &As[hf][(r * 64 + w * 16) * 32]);
        async16(Bg + (long)r * 64 * K + k0 + hf * 32,
                &Bs[hf][(r * 64 + w * 16) * 32]);
      }
    __syncthreads();

#pragma unroll
    for (int hf = 0; hf < 2; hf++) {
      bf16x8 a[4], b[4];
#pragma unroll
      for (int ii = 0; ii < 4; ii++)
        a[ii] = ldsld8(&As[hf][(wr * 64 + ii * 16 + lane15) * 32 + quad * 8]);
#pragma unroll
      for (int j = 0; j < 4; j++)
        b[j] = ldsld8(&Bs[hf][(wc * 64 + j * 16 + lane15) * 32 + quad * 8]);
#pragma unroll
      for (int ii = 0; ii < 4; ii++)
#pragma unroll
        for (int j = 0; j < 4; j++) acc[ii][j] = mfma16(a[ii], b[j], acc[ii][j]);
    }
  }

  if (col0 >= 1024) {
    // V part -> transposed: vT[(b*512 + hd)*2048 + s], 4 s-consecutive per store
#pragma unroll
    for (int ii = 0; ii < 4; ii++)
#pragma unroll
      for (int j = 0; j < 4; j++) {
        const int hd = col0 - 1024 + wc * 64 + j * 16 + lane15;
        const long row = row0 + wr * 64 + ii * 16 + quad * 4;
        const long bb = row >> 11;
        const int s = (int)(row & 2047);
        u32x2 pr;
        pr[0] = pk2(acc[ii][j][0], acc[ii][j][1]);
        pr[1] = pk2(acc[ii][j][2], acc[ii][j][3]);
        *(u16x4*)(vT + (bb * 512 + hd) * 2048 + s) =
            __builtin_bit_cast(u16x4, pr);
      }
  } else {
    // Q/K part -> qk (LD=1024); q cols pre-scaled for attn's exp2
#pragma unroll
    for (int ii = 0; ii < 4; ii++)
#pragma unroll
      for (int j = 0; j < 4; j++) {
        const int col = col0 + wc * 64 + j * 16 + lane15;
        const float sc = (col < 512) ? 0.18033688f : 1.0f;
#pragma unroll
        for (int r = 0; r < 4; r++) {
          const long row = row0 + wr * 64 + ii * 16 + quad * 4 + r;
          qk[row * 1024 + col] = f2b(acc[ii][j][r] * sc);
        }
      }
  }
}

// ---------------------------------------------------------------------------
// gemm3: C[M,512](fp32) = A[M,512](bf16) @ Bt[512,512](fp32)^T + bias.
// BM=128, BN=64, BK=64; XCD-swizzled. (R8/R13-proven)
// ---------------------------------------------------------------------------
__global__ void gemm_b64(const u16* __restrict__ A, const float* __restrict__ Bt,
                         const float* __restrict__ bias, float* __restrict__ C,
                         int N, int K) {
  __shared__ __align__(16) u16 As[2][128 * 32];
  __shared__ __align__(16) u16 Bs[2][64 * 32];

  const int t = threadIdx.x, lane = t & 63, w = t >> 6;
  const int lane15 = lane & 15, quad = lane >> 4;
  const int wr = w >> 1, wc = w & 1;

  const int i = blockIdx.x;
  const int rt = (i & 7) | (((i >> 3) & 7) << 3);
  const int ct = i >> 6;
  const long row0 = (long)rt * 128;
  const int col0 = ct * 64;

  const int srow = w * 16 + (lane >> 2);
  const int scol = (lane & 3) * 8;
  const u16* Ag = A + (row0 + srow) * (long)K + scol;

  const int brow = t >> 2, bc = (t & 3) * 16;
  const float* Bg = Bt + (long)(col0 + brow) * K + bc;
  u16* BsD = &Bs[bc >> 5][brow * 32 + (bc & 31)];

  f32x4 acc[4][2];
#pragma unroll
  for (int ii = 0; ii < 4; ii++)
#pragma unroll
    for (int j = 0; j < 2; j++) acc[ii][j] = (f32x4)(0.0f);

  f32x4 q0 = *(const f32x4*)Bg, q1 = *(const f32x4*)(Bg + 4);
  f32x4 q2 = *(const f32x4*)(Bg + 8), q3 = *(const f32x4*)(Bg + 12);

  for (int k0 = 0; k0 < K; k0 += 64) {
    __syncthreads();
#pragma unroll
    for (int r = 0; r < 2; r++)
#pragma unroll
      for (int hf = 0; hf < 2; hf++)
        async16(Ag + (long)r * 64 * K + k0 + hf * 32,
                &As[hf][(r * 64 + w * 16) * 32]);
    lst8(BsD, pack8(q0, q1));
    lst8(BsD + 8, pack8(q2, q3));
    __syncthreads();

    {
      const int kp = (k0 + 64 < K) ? k0 + 64 : k0;
      q0 = *(const f32x4*)(Bg + kp);     q1 = *(const f32x4*)(Bg + kp + 4);
      q2 = *(const f32x4*)(Bg + kp + 8); q3 = *(const f32x4*)(Bg + kp + 12);
    }

#pragma unroll
    for (int hf = 0; hf < 2; hf++) {
      bf16x8 a[4], b[2];
#pragma unroll
      for (int ii = 0; ii < 4; ii++)
        a[ii] = ldsld8(&As[hf][(wr * 64 + ii * 16 + lane15) * 32 + quad * 8]);
#pragma unroll
      for (int j = 0; j < 2; j++)
        b[j] = ldsld8(&Bs[hf][(wc * 32 + j * 16 + lane15) * 32 + quad * 8]);
#pragma unroll
      for (int ii = 0; ii < 4; ii++)
#pragma unroll
        for (int j = 0; j < 2; j++) acc[ii][j] = mfma16(a[ii], b[j], acc[ii][j]);
    }
  }

#pragma unroll
  for (int ii = 0; ii < 4; ii++)
#pragma unroll
    for (int j = 0; j < 2; j++) {
      const int col = col0 + wc * 32 + j * 16 + lane15;
      const float bv = bias[col];
#pragma unroll
      for (int r = 0; r < 4; r++) {
        const long row = row0 + wr * 64 + ii * 16 + quad * 4 + r;
        C[row * (long)N + col] = acc[ii][j][r] + bv;
      }
    }
}

// ---------------------------------------------------------------------------
// attn_v6: v3 skeleton; K from qk (LD=1024), V^T from vT — both staged as
// b128 rows into pad-72 LDS (no in-kernel transpose, no swizzle). P-store
// packed via pk2. q pre-scaled -> exp2 direct. 1024 blocks, 256 threads.
// ---------------------------------------------------------------------------
__global__ void attn_v6(const u16* __restrict__ qk, const u16* __restrict__ vT,
                        u16* __restrict__ out) {
  constexpr int T = 2048, LDQ = 1024;
  __shared__ __align__(16) u16 Ks[64 * 72];
  __shared__ __align__(16) u16 Vs[64 * 72];  // V^T rows: Vs[d][s]
  __shared__ __align__(16) u16 Ps[4][16 * 72];

  const int t = threadIdx.x, lane = t & 63, w = t >> 6;
  const int lane15 = lane & 15, quad = lane >> 4;

  const int i = blockIdx.x;
  int qb = i & 31;
  if (i >= 512) qb = 31 - qb;  // load-balance
  const int h = (i >> 5) & 7;
  const int b = (i >> 8) & 3;
  const long baseq = (long)b * T * LDQ;
  const u16* vTb = vT + ((long)b * 512 + h * 64) * 2048;  // rows d, stride 2048

  const u16* gq =
      qk + baseq + (long)(qb * 64 + w * 16 + lane15) * LDQ + h * 64 + quad * 8;
  const bf16x8 qa0 = __builtin_bit_cast(bf16x8, *(const u16x8*)gq);
  const bf16x8 qa1 = __builtin_bit_cast(bf16x8, *(const u16x8*)(gq + 32));

  const int srow = t >> 3, sc8 = (t & 7) * 8;  // rows {srow, srow+32}

  const int nsb = qb + 1;

  u16x8 kr0, kr1, vr0, vr1;  // prefetch s-tile 0
  {
    const u16* gk = qk + baseq + (long)srow * LDQ + 512 + h * 64 + sc8;
    kr0 = gld8(gk); kr1 = gld8(gk + (long)32 * LDQ);
    const u16* gv = vTb + (long)srow * 2048 + sc8;
    vr0 = gld8(gv); vr1 = gld8(gv + (long)32 * 2048);
  }

  float lp[4] = {0.0f, 0.0f, 0.0f, 0.0f};
  f32x4 o[4];
#pragma unroll
  for (int j = 0; j < 4; j++) o[j] = (f32x4)(0.0f);

  const int qrow_base = qb * 64 + w * 16 + quad * 4;

  for (int sb = 0; sb < nsb; ++sb) {
    __syncthreads();  // previous iteration's LDS reads complete
    lst8(&Ks[srow * 72 + sc8], kr0);
    lst8(&Ks[(srow + 32) * 72 + sc8], kr1);
    lst8(&Vs[srow * 72 + sc8], vr0);
    lst8(&Vs[(srow + 32) * 72 + sc8], vr1);
    __syncthreads();  // tiles visible

    {  // prefetch next s-tile under compute (clamped)
      const int sp = (sb + 1 < nsb) ? sb + 1 : sb;
      const u16* gk =
          qk + baseq + (long)(sp * 64 + srow) * LDQ + 512 + h * 64 + sc8;
      kr0 = gld8(gk); kr1 = gld8(gk + (long)32 * LDQ);
      const u16* gv = vTb + (long)srow * 2048 + sp * 64 + sc8;
      vr0 = gld8(gv); vr1 = gld8(gv + (long)32 * 2048);
    }

    // S strip (16 q x 64 s)
    f32x4 sf[4];
#pragma unroll
    for (int j = 0; j < 4; j++) {
      f32x4 z = (f32x4)(0.0f);
      z = mfma16(qa0, ldsld8(&Ks[(j * 16 + lane15) * 72 + quad * 8]), z);
      sf[j] = mfma16(qa1, ldsld8(&Ks[(j * 16 + lane15) * 72 + quad * 8 + 32]), z);
    }

    // p = exp2(s); causal zeroing on diag block only
    if (sb == qb) {
      const int scol_base = sb * 64 + lane15;
#pragma unroll
      for (int j = 0; j < 4; j++)
#pragma unroll
        for (int r = 0; r < 4; r++) {
          float p = exp2f(sf[j][r]);
          if (scol_base + j * 16 > qrow_base + r) p = 0.0f;
          sf[j][r] = p;
          lp[r] += p;
        }
    } else {
#pragma unroll
      for (int j = 0; j < 4; j++)
#pragma unroll
        for (int r = 0; r < 4; r++) {
          const float p = exp2f(sf[j][r]);
          sf[j][r] = p;
          lp[r] += p;
        }
    }

    // P: C-layout -> per-wave LDS -> A-layout; pk2-packed conversion
    u16* myP = Ps[w];
#pragma unroll
    for (int r = 0; r < 4; r++) {
      const int ro = (quad * 4 + r) * 72 + lane15;
      const unsigned v01 = pk2(sf[0][r], sf[1][r]);
      const unsigned v23 = pk2(sf[2][r], sf[3][r]);
      myP[ro] = (u16)v01;
      myP[ro + 16] = (u16)(v01 >> 16);
      myP[ro + 32] = (u16)v23;
      myP[ro + 48] = (u16)(v23 >> 16);
    }
    __asm__ __volatile__("" ::: "memory");
    const bf16x8 pa0 = ldsld8(&myP[lane15 * 72 + quad * 8]);
    const bf16x8 pa1 = ldsld8(&myP[lane15 * 72 + quad * 8 + 32]);
    __asm__ __volatile__("" ::: "memory");

    // O += P @ V from Vs (V^T rows; plain b128, quarter-wave 2-way = free)
#pragma unroll
    for (int j = 0; j < 4; j++) {
      const int d0 = (j * 16 + lane15) * 72;
      o[j] = mfma16(pa0, ldsld8(&Vs[d0 + quad * 8]), o[j]);
      o[j] = mfma16(pa1, ldsld8(&Vs[d0 + quad * 8 + 32]), o[j]);
    }
  }

#pragma unroll
  for (int off = 1; off < 16; off <<= 1)
#pragma unroll
    for (int r = 0; r < 4; r++) lp[r] += __shfl_xor(lp[r], off);

  const long orow0 = (long)b * T + qb * 64 + w * 16;
  float inv[4];
#pragma unroll
  for (int r = 0; r < 4; r++) inv[r] = 1.0f / lp[r];
#pragma unroll
  for (int j = 0; j < 4; j++)
#pragma unroll
    for (int r = 0; r < 4; r++)
      out[(orow0 + quad * 4 + r) * 512 + h * 64 + j * 16 + lane15] =
          f2b(o[j][r] * inv[r]);
}

// ---------------------------------------------------------------------------
extern "C" void kernel_launch(void* const* d_in, const int* in_sizes, int n_in,
                              void* d_out, int out_size, void* d_ws, size_t ws_size,
                              hipStream_t stream) {
  const float* x      = (const float*)d_in[0];  // [4,2048,512] fp32
  const float* w_qkv  = (const float*)d_in[1];  // [1536,512]  fp32
  const float* w_proj = (const float*)d_in[2];  // [512,512]   fp32
  const float* b_proj = (const float*)d_in[3];  // [512]       fp32
  float* out = (float*)d_out;                   // [4,2048,512] fp32

  u16* qk = (u16*)d_ws;                   // [8192 x 1024] bf16 = 16 MiB
  u16* vT = qk + (size_t)8192 * 1024;     // [4 x 512 x 2048] bf16 = 8 MiB
  u16* xb = vT + (size_t)4 * 512 * 2048;  // [8192 x 512] bf16 = 8 MiB
                                          // (x_bf16, then attn output)
  u16* wqb = (u16*)d_out;                 // w_qkv bf16 parked in d_out

  // [0] convert x and w_qkv to bf16
  cvt_all<<<2432, 256, 0, stream>>>(x, w_qkv, xb, wqb);
  // [1] qkv projection: qk + transposed vT
  gemm_bb<<<768, 256, 0, stream>>>(xb, wqb, qk, vT, 512);
  // [2] causal flash attention (overwrites xb)
  attn_v6<<<1024, 256, 0, stream>>>(qk, vT, xb);
  // [3] output projection + bias -> fp32 d_out
  gemm_b64<<<512, 256, 0, stream>>>(xb, w_proj, b_proj, out, 512, 512);
}